// Round 1
// baseline (98.387 us; speedup 1.0000x reference)
//
#include <hip/hip_runtime.h>

#define IMGSZ 448.0f
#define HH 28
#define WW 28
#define AA 5
#define CC 80
#define BB 128
#define NN 50
#define HW (HH * WW)
#define NCELL (BB * AA * HW)   // 501760

__device__ __forceinline__ float sigf(float x) {
    return 1.0f / (1.0f + __expf(-x));
}

// block-wide reduce of a double, one atomicAdd per block
__device__ __forceinline__ void block_acc(double v, double* acc) {
    #pragma unroll
    for (int o = 32; o > 0; o >>= 1) v += __shfl_down(v, o, 64);
    __shared__ double s[8];
    int lane = threadIdx.x & 63, wid = threadIdx.x >> 6;
    if (lane == 0) s[wid] = v;
    __syncthreads();
    if (threadIdx.x == 0) {
        double t = 0.0;
        int nw = (blockDim.x + 63) >> 6;
        for (int i = 0; i < nw; ++i) t += s[i];
        atomicAdd(acc, t);
    }
}

// ---- kernel 1: 0.5 * sigmoid(conf)^2 over ALL cells (noobj baseline) ----
__global__ void noobj_kernel(const float* __restrict__ out, double* __restrict__ acc) {
    int t = blockIdx.x * blockDim.x + threadIdx.x;
    double v = 0.0;
    if (t < NCELL) {
        int ba = t / HW;           // b*A + a
        int hw = t - ba * HW;
        float x = out[(size_t)(ba * 85 + 4) * HW + hw];
        float s = sigf(x);
        v = 0.5 * (double)(s * s);
    }
    block_acc(v, acc);
}

// compute (best_anchor, gi, gj) for one box
__device__ __forceinline__ int cell_of(const float* __restrict__ anc,
                                       float bx, float by, float bw, float bh,
                                       int* pgi, int* pgj) {
    float gtw = bw * IMGSZ, gth = bh * IMGSZ;
    float gt_area = gtw * gth;
    int best = 0;
    float best_iou = -1.0f;
    #pragma unroll
    for (int k = 0; k < AA; ++k) {
        float aw = anc[2 * k], ah = anc[2 * k + 1];
        float inter = fminf(gtw, aw) * fminf(gth, ah);
        float iou = inter / (gt_area + aw * ah - inter);
        if (iou > best_iou) { best_iou = iou; best = k; }
    }
    float gx = bx * WW, gy = by * HH;
    int gi = (int)gx; gi = gi < 0 ? 0 : (gi > WW - 1 ? WW - 1 : gi);
    int gj = (int)gy; gj = gj < 0 ? 0 : (gj > HH - 1 ? HH - 1 : gj);
    *pgi = gi; *pgj = gj;
    return best;
}

// ---- kernel 2: per-GT-box obj-cell contributions (dedup: largest n wins) ----
__global__ void box_kernel(const float* __restrict__ out,
                           const float* __restrict__ boxes,
                           const int* __restrict__ cls,
                           const float* __restrict__ anchors,
                           double* __restrict__ acc) {
    int t = blockIdx.x * blockDim.x + threadIdx.x;
    double v = 0.0;
    if (t < BB * NN) {
        int b = t / NN, n = t - b * NN;
        // local copy of anchors (10 floats, L1-resident anyway)
        float anc[2 * AA];
        #pragma unroll
        for (int i = 0; i < 2 * AA; ++i) anc[i] = anchors[i];

        const float* bx0 = boxes + (size_t)t * 4;
        float bx = bx0[0], by = bx0[1], bw = bx0[2], bh = bx0[3];
        int gi, gj;
        int best = cell_of(anc, bx, by, bw, bh, &gi, &gj);

        // dedup: skip if ANY later box in this batch maps to the same cell
        bool alive = true;
        const float* bb = boxes + (size_t)(b * NN) * 4;
        for (int n2 = n + 1; n2 < NN && alive; ++n2) {
            int gi2, gj2;
            int best2 = cell_of(anc, bb[4 * n2], bb[4 * n2 + 1],
                                bb[4 * n2 + 2], bb[4 * n2 + 3], &gi2, &gj2);
            if (best2 == best && gi2 == gi && gj2 == gj) alive = false;
        }

        if (alive) {
            size_t base = ((size_t)(b * AA + best) * 85) * HW + (size_t)gj * WW + gi;
            float ptx = sigf(out[base + 0 * HW]);
            float pty = sigf(out[base + 1 * HW]);
            float ptw = out[base + 2 * HW];
            float pth = out[base + 3 * HW];
            float pc  = sigf(out[base + 4 * HW]);

            float gx = bx * WW, gy = by * HH;
            float tx = gx - (float)gi, ty = gy - (float)gj;
            float saw = anc[2 * best] / 16.0f;   // stride = 448/28 = 16
            float sah = anc[2 * best + 1] / 16.0f;
            float tw = logf(bw * WW / saw + 1e-16f);
            float th = logf(bh * HH / sah + 1e-16f);

            float dtx = ptx - tx, dty = pty - ty, dtw = ptw - tw, dth = pth - th;
            float coord = 5.0f * (dtx * dtx + dty * dty + dtw * dtw + dth * dth);
            float confadj = (pc - 1.0f) * (pc - 1.0f) - 0.5f * pc * pc;

            // class NLL: stable log_softmax over 80 logits (stride HW)
            const float* cl = out + base + 5 * HW;
            float m = -3.4e38f;
            for (int c = 0; c < CC; ++c) m = fmaxf(m, cl[(size_t)c * HW]);
            float se = 0.0f;
            for (int c = 0; c < CC; ++c) se += __expf(cl[(size_t)c * HW] - m);
            float lse = m + logf(se);
            int tc = cls[t];
            float nll = lse - cl[(size_t)tc * HW];

            v = (double)coord + (double)confadj + (double)nll;
        }
    }
    block_acc(v, acc);
}

// ---- kernel 3: finalize ----
__global__ void finalize_kernel(const double* __restrict__ acc, float* __restrict__ out) {
    if (threadIdx.x == 0 && blockIdx.x == 0)
        out[0] = (float)(acc[0] / (double)BB);
}

extern "C" void kernel_launch(void* const* d_in, const int* in_sizes, int n_in,
                              void* d_out, int out_size, void* d_ws, size_t ws_size,
                              hipStream_t stream) {
    const float* output  = (const float*)d_in[0];
    const float* boxes   = (const float*)d_in[1];
    const int*   cls     = (const int*)d_in[2];
    const float* anchors = (const float*)d_in[3];
    float* out = (float*)d_out;
    double* acc = (double*)d_ws;

    hipMemsetAsync(d_ws, 0, sizeof(double), stream);

    noobj_kernel<<<(NCELL + 255) / 256, 256, 0, stream>>>(output, acc);
    box_kernel<<<(BB * NN + 255) / 256, 256, 0, stream>>>(output, boxes, cls, anchors, acc);
    finalize_kernel<<<1, 1, 0, stream>>>(acc, out);
}